// Round 13
// baseline (203.929 us; speedup 1.0000x reference)
//
#include <hip/hip_runtime.h>

// ---------------------------------------------------------------------------
// Compile-time Clebsch-Gordan / real-basis Wigner-3j generation (exact port of
// the Python reference: _cg_coef, _su2_cg, _q, _w3j, normalization, pw).
// ---------------------------------------------------------------------------

struct W3JT { double v[9][9][9]; };

constexpr double dfact(int n) { double r = 1.0; for (int i = 2; i <= n; ++i) r *= (double)i; return r; }

constexpr double csqrt(double x) {
  if (x <= 0.0) return 0.0;
  double g = x > 1.0 ? x : 1.0;
  for (int i = 0; i < 80; ++i) g = 0.5 * (g + x / g);
  return g;
}

constexpr double cg_coef(int j1, int m1, int j2, int m2, int j3, int m3) {
  if (m1 + m2 != m3) return 0.0;
  int vmin = 0;
  if (j2 - j3 - m1 > vmin) vmin = j2 - j3 - m1;
  if (j1 - j3 + m2 > vmin) vmin = j1 - j3 + m2;
  int vmax = j1 + j2 - j3;
  if (j1 - m1 < vmax) vmax = j1 - m1;
  if (j2 + m2 < vmax) vmax = j2 + m2;
  double pref = csqrt((2.0 * j3 + 1.0) * dfact(j3 + j1 - j2) * dfact(j3 - j1 + j2) * dfact(j1 + j2 - j3) / dfact(j1 + j2 + j3 + 1));
  pref *= csqrt(dfact(j3 + m3) * dfact(j3 - m3) * dfact(j1 + m1) * dfact(j1 - m1) * dfact(j2 + m2) * dfact(j2 - m2));
  double s = 0.0;
  for (int v = vmin; v <= vmax; ++v) {
    double t = 1.0 / (dfact(v) * dfact(j1 + j2 - j3 - v) * dfact(j1 - m1 - v) * dfact(j2 + m2 - v) * dfact(j3 - j2 + m1 + v) * dfact(j3 - j1 - m2 + v));
    s += (v & 1) ? -t : t;
  }
  return pref * s;
}

// Nonzero rows of column `col` of the complex->real change-of-basis matrix
// q(l) (each column has <=2 nonzeros), with the (-i)^l phase applied.
struct QCol { int n; int row[2]; double re[2]; double im[2]; };

constexpr QCol qcol(int l, int col) {
  QCol q{};
  const int lm = l & 3;
  const double pr = (lm == 0) ? 1.0 : (lm == 2) ? -1.0 : 0.0;   // Re((-i)^l)
  const double pi = (lm == 1) ? -1.0 : (lm == 3) ? 1.0 : 0.0;   // Im((-i)^l)
  const int mu = col - l;
  const int am = mu < 0 ? -mu : mu;
  const double is2 = 0.70710678118654752440;
  if (mu == 0) {
    q.n = 1; q.row[0] = l;
    q.re[0] = pr; q.im[0] = pi;
  } else {
    const double s = (am & 1) ? -1.0 : 1.0;   // (-1)^|m|
    double a0 = 0.0, b0 = 0.0, a1 = 0.0, b1 = 0.0;
    if (mu > 0) { a0 = is2; b0 = 0.0;  a1 = s * is2; b1 = 0.0; }      // col l+|m|
    else        { a0 = 0.0; b0 = -is2; a1 = 0.0;     b1 = s * is2; }  // col l-|m|
    q.n = 2;
    q.row[0] = l - am; q.row[1] = l + am;
    q.re[0] = a0 * pr - b0 * pi; q.im[0] = a0 * pi + b0 * pr;
    q.re[1] = a1 * pr - b1 * pi; q.im[1] = a1 * pi + b1 * pr;
  }
  return q;
}

constexpr W3JT make_w3j(int l1, int l2, int l3) {
  W3JT R{};
  double C[9][9][9]{};
  for (int m1 = -l1; m1 <= l1; ++m1)
    for (int m2 = -l2; m2 <= l2; ++m2) {
      int m3 = m1 + m2;
      if (m3 >= -l3 && m3 <= l3)
        C[l1 + m1][l2 + m2][l3 + m3] = cg_coef(l1, m1, l2, m2, l3, m3);
    }
  // C_real[j][l][m] = Re( sum q1[i][j] q2[k][l] conj(q3[n][m]) C[i][k][n] )
  double nrm = 0.0;
  for (int j = 0; j < 2 * l1 + 1; ++j) {
    QCol q1 = qcol(l1, j);
    for (int l = 0; l < 2 * l2 + 1; ++l) {
      QCol q2 = qcol(l2, l);
      for (int m = 0; m < 2 * l3 + 1; ++m) {
        QCol q3 = qcol(l3, m);
        double re = 0.0;
        for (int a = 0; a < q1.n; ++a)
          for (int b = 0; b < q2.n; ++b)
            for (int c = 0; c < q3.n; ++c) {
              double cv = C[q1.row[a]][q2.row[b]][q3.row[c]];
              if (cv == 0.0) continue;
              double ar = q1.re[a], ai = q1.im[a];
              double br = q2.re[b], bi = q2.im[b];
              double cr = q3.re[c], ci = -q3.im[c];   // conj
              double abr = ar * br - ai * bi;
              double abi = ar * bi + ai * br;
              double prr = abr * cr - abi * ci;       // Re(triple product)
              re += prr * cv;
            }
        R.v[j][l][m] = re;
        nrm += re * re;
      }
    }
  }
  double n = csqrt(nrm);
  if (n > 0.0)
    for (int j = 0; j < 2 * l1 + 1; ++j)
      for (int l = 0; l < 2 * l2 + 1; ++l)
        for (int m = 0; m < 2 * l3 + 1; ++m)
          R.v[j][l][m] /= n;
  return R;
}

// instruction counts per output-l (verified against the reference enumeration)
// INS1  = instructions(3,3,4): c-counts {4,6,7,6,4}
// INS21 = instructions(3,4,3): c-counts {4,7,8,8}   (INS22 identical)
constexpr int CNT1[5] = {4, 6, 7, 6, 4};
constexpr int CNT2[4] = {4, 7, 8, 8};

#define NZCHK(V) ((V) > 1e-12 || (V) < -1e-12)

// LDS-resident xm/ym accessors for chain lane q (v6 rotate swizzle)
#define LXM(J) lmx[q * 32 + (((J) + q) & 31)]
#define LYM(J) lmx[q * 32 + ((16 + (J) + q) & 31)]

// MID-phase TP, c-grouped: accumulate into slice ACC[0..2C], xm/ym from LDS.
#define TPM(IDX, A, B, C, ACC) do { \
  constexpr W3JT T = make_w3j(A, B, C); \
  constexpr double PW = csqrt((2.0 * (C) + 1.0) / (double)CNT1[(C)]); \
  const float wi = w1p[IDX]; \
  float u_[2 * (A) + 1], yv_[2 * (B) + 1]; \
  _Pragma("unroll") for (int i = 0; i < 2 * (A) + 1; ++i) u_[i] = wi * LXM((A) * (A) + i); \
  _Pragma("unroll") for (int j = 0; j < 2 * (B) + 1; ++j) yv_[j] = LYM((B) * (B) + j); \
  _Pragma("unroll") for (int i = 0; i < 2 * (A) + 1; ++i) { \
    _Pragma("unroll") for (int j = 0; j < 2 * (B) + 1; ++j) { \
      const float p_ = u_[i] * yv_[j]; \
      _Pragma("unroll") for (int k = 0; k < 2 * (C) + 1; ++k) { \
        if (NZCHK(T.v[i][j][k])) \
          ACC[k] = __builtin_fmaf((float)(T.v[i][j][k] * PW), p_, ACC[k]); \
      } \
    } \
  } \
} while (0)

// OUT-phase TP, c-grouped: u = w21*xm + w22*ym (LDS), mid slice from LDS.
#define TPO(IDX, A, B, C, ACC) do { \
  constexpr W3JT T = make_w3j(A, B, C); \
  constexpr double PW = csqrt((2.0 * (C) + 1.0) / (double)CNT2[(C)]); \
  const float wa = w21p[IDX]; \
  const float wb = w22p[IDX]; \
  float u_[2 * (A) + 1], mv_[2 * (B) + 1]; \
  _Pragma("unroll") for (int i = 0; i < 2 * (A) + 1; ++i) \
    u_[i] = wa * LXM((A) * (A) + i) + wb * LYM((A) * (A) + i); \
  _Pragma("unroll") for (int j = 0; j < 2 * (B) + 1; ++j) mv_[j] = lmid[q * 27 + (B) * (B) + j]; \
  _Pragma("unroll") for (int i = 0; i < 2 * (A) + 1; ++i) { \
    _Pragma("unroll") for (int j = 0; j < 2 * (B) + 1; ++j) { \
      const float p_ = u_[i] * mv_[j]; \
      _Pragma("unroll") for (int k = 0; k < 2 * (C) + 1; ++k) { \
        if (NZCHK(T.v[i][j][k])) \
          ACC[k] = __builtin_fmaf((float)(T.v[i][j][k] * PW), p_, ACC[k]); \
      } \
    } \
  } \
} while (0)

// bf16 pack/unpack (RNE) for the s = x+y payload
__device__ __forceinline__ unsigned int bfr(float f) {
  unsigned int u = __builtin_bit_cast(unsigned int, f);
  return (u + 0x7fffu + ((u >> 16) & 1u)) >> 16;
}
__device__ __forceinline__ unsigned int pkbf(float a, float b) {
  return bfr(a) | (bfr(b) << 16);
}
__device__ __forceinline__ float ubl(unsigned int u) { return __builtin_bit_cast(float, u << 16); }
__device__ __forceinline__ float ubh(unsigned int u) { return __builtin_bit_cast(float, u & 0xffff0000u); }

// ---------------------------------------------------------------------------
// v18: 2 edges per thread -> half the waves (6252 vs v6's 12500), 2x memory
// streams per thread. v6's exact per-edge addressing (the only traffic-clean
// pattern). VGPR control: s payload packed bf16 (64 u32 for both edges);
// means written to LDS per-k (no px/py arrays); chain c-grouped with mid/tv
// slices (<=9 regs live) flushed through LDS; xm/ym read from LDS on demand.
//  phase 1: interleaved loads of edges eL and eL+64; s->bf16 regs; inline quad
//           butterfly -> row means -> LDS (rotate swizzle).
//  phase 2: threads 0..127, one edge each: c-grouped constant-folded chain.
//  phase 3: out = unpack(s) + tv[row], single store per edge.
// ---------------------------------------------------------------------------
__global__ __launch_bounds__(256) void cg2_v18(
    const float4* __restrict__ x4, const float4* __restrict__ y4,
    const float* __restrict__ w1p, const float* __restrict__ w21p,
    const float* __restrict__ w22p, float4* __restrict__ o4, int E)
{
  __shared__ float lmx[128 * 32];   // xm/ym per edge-in-block (rotate swizzle)
  __shared__ float lmid[128 * 27];  // mid[25] per edge (stride 27, bank-clean)
  __shared__ float ltv[128 * 16];   // tv per edge (v6 swizzle)

  const int eL = threadIdx.x >> 2;        // 0..63
  const int g  = threadIdx.x & 3;         // quad lane
  const int e0 = blockIdx.x * 128;
  const int eA = e0 + eL;                 // first edge of this thread
  const int eB = eA + 64;                 // second edge
  const bool okA = (eA < E), okB = (eB < E);
  const int baseA = eA * 64 + g;
  const int baseB = eB * 64 + g;

  // ---- phase 1: dual-stream loads, bf16 s, inline butterfly, means->LDS ----
  unsigned int sA0[16], sA1[16], sB0[16], sB1[16];
#pragma unroll
  for (int k = 0; k < 16; ++k) {
    float pxa = 0.f, pya = 0.f, pxb = 0.f, pyb = 0.f;
    if (okA) {
      const float4 xv = x4[baseA + 4 * k];
      const float4 yv = y4[baseA + 4 * k];
      sA0[k] = pkbf(xv.x + yv.x, xv.y + yv.y);
      sA1[k] = pkbf(xv.z + yv.z, xv.w + yv.w);
      pxa = (xv.x + xv.y) + (xv.z + xv.w);
      pya = (yv.x + yv.y) + (yv.z + yv.w);
    }
    if (okB) {
      const float4 xv = x4[baseB + 4 * k];
      const float4 yv = y4[baseB + 4 * k];
      sB0[k] = pkbf(xv.x + yv.x, xv.y + yv.y);
      sB1[k] = pkbf(xv.z + yv.z, xv.w + yv.w);
      pxb = (xv.x + xv.y) + (xv.z + xv.w);
      pyb = (yv.x + yv.y) + (yv.z + yv.w);
    }
    // quad butterflies (all 4 lanes end with the row sum)
    pxa += __shfl_xor(pxa, 1); pxa += __shfl_xor(pxa, 2);
    pya += __shfl_xor(pya, 1); pya += __shfl_xor(pya, 2);
    pxb += __shfl_xor(pxb, 1); pxb += __shfl_xor(pxb, 2);
    pyb += __shfl_xor(pyb, 1); pyb += __shfl_xor(pyb, 2);
    if (g == 0) {
      const int sw  = (k + eL) & 31;        // same for eL and eL+64 (64%32==0)
      const int swy = (16 + k + eL) & 31;
      if (okA) {
        lmx[eL * 32 + sw]  = pxa * (1.0f / 16.0f);
        lmx[eL * 32 + swy] = pya * (1.0f / 16.0f);
      }
      if (okB) {
        lmx[(eL + 64) * 32 + sw]  = pxb * (1.0f / 16.0f);
        lmx[(eL + 64) * 32 + swy] = pyb * (1.0f / 16.0f);
      }
    }
  }
  __syncthreads();

  // ---- phase 2: threads 0..127 run the c-grouped chain, one edge each ----
  if (threadIdx.x < 128) {
    const int q = threadIdx.x;
    const bool okq = (e0 + q) < E;
    if (okq) {
      // MID groups by output c (slices of mid[c*c .. c*c+2c])
      { float m0[1] = {0.f};
        TPM( 0,0,0,0,m0); TPM( 5,1,1,0,m0); TPM(14,2,2,0,m0); TPM(24,3,3,0,m0);
        lmid[q * 27 + 0] = m0[0]; }
      { float m1[3] = {0.f,0.f,0.f};
        TPM( 1,0,1,1,m1); TPM( 4,1,0,1,m1); TPM( 7,1,2,1,m1);
        TPM(12,2,1,1,m1); TPM(17,2,3,1,m1); TPM(22,3,2,1,m1);
#pragma unroll
        for (int i = 0; i < 3; ++i) lmid[q * 27 + 1 + i] = m1[i]; }
      { float m2[5] = {0.f,0.f,0.f,0.f,0.f};
        TPM( 2,0,2,2,m2); TPM( 6,1,1,2,m2); TPM( 9,1,3,2,m2); TPM(11,2,0,2,m2);
        TPM(15,2,2,2,m2); TPM(20,3,1,2,m2); TPM(25,3,3,2,m2);
#pragma unroll
        for (int i = 0; i < 5; ++i) lmid[q * 27 + 4 + i] = m2[i]; }
      { float m3[7] = {0.f,0.f,0.f,0.f,0.f,0.f,0.f};
        TPM( 3,0,3,3,m3); TPM( 8,1,2,3,m3); TPM(13,2,1,3,m3);
        TPM(18,2,3,3,m3); TPM(19,3,0,3,m3); TPM(23,3,2,3,m3);
#pragma unroll
        for (int i = 0; i < 7; ++i) lmid[q * 27 + 9 + i] = m3[i]; }
      { float m4[9] = {0.f,0.f,0.f,0.f,0.f,0.f,0.f,0.f,0.f};
        TPM(10,1,3,4,m4); TPM(16,2,2,4,m4); TPM(21,3,1,4,m4); TPM(26,3,3,4,m4);
#pragma unroll
        for (int i = 0; i < 9; ++i) lmid[q * 27 + 16 + i] = m4[i]; }

      asm volatile("" ::: "memory");   // block LDS store->load forwarding

      // OUT groups by output c; tv slices -> ltv (v6 swizzle)
      { float t0[1] = {0.f};
        TPO( 0,0,0,0,t0); TPO( 5,1,1,0,t0); TPO(14,2,2,0,t0); TPO(23,3,3,0,t0);
        ltv[q * 16 + ((0 + q) & 15)] = t0[0]; }
      { float t1[3] = {0.f,0.f,0.f};
        TPO( 1,0,1,1,t1); TPO( 4,1,0,1,t1); TPO( 7,1,2,1,t1); TPO(12,2,1,1,t1);
        TPO(16,2,3,1,t1); TPO(21,3,2,1,t1); TPO(25,3,4,1,t1);
#pragma unroll
        for (int i = 0; i < 3; ++i) ltv[q * 16 + ((1 + i + q) & 15)] = t1[i]; }
      { float t2[5] = {0.f,0.f,0.f,0.f,0.f};
        TPO( 2,0,2,2,t2); TPO( 6,1,1,2,t2); TPO( 9,1,3,2,t2); TPO(11,2,0,2,t2);
        TPO(15,2,2,2,t2); TPO(18,2,4,2,t2); TPO(20,3,1,2,t2); TPO(24,3,3,2,t2);
#pragma unroll
        for (int i = 0; i < 5; ++i) ltv[q * 16 + ((4 + i + q) & 15)] = t2[i]; }
      { float t3[7] = {0.f,0.f,0.f,0.f,0.f,0.f,0.f};
        TPO( 3,0,3,3,t3); TPO( 8,1,2,3,t3); TPO(10,1,4,3,t3); TPO(13,2,1,3,t3);
        TPO(17,2,3,3,t3); TPO(19,3,0,3,t3); TPO(22,3,2,3,t3); TPO(26,3,4,3,t3);
#pragma unroll
        for (int i = 0; i < 7; ++i) ltv[q * 16 + ((9 + i + q) & 15)] = t3[i]; }
    }
  }
  __syncthreads();

  // ---- phase 3: out = unpack(s) + tv[row], one store per edge ----
#pragma unroll
  for (int k = 0; k < 16; ++k) {
    const int sw = (k + eL) & 15;            // same for eL and eL+64 (64%16==0)
    if (okA) {
      const float t = ltv[eL * 16 + sw];
      float4 o;
      o.x = ubl(sA0[k]) + t; o.y = ubh(sA0[k]) + t;
      o.z = ubl(sA1[k]) + t; o.w = ubh(sA1[k]) + t;
      o4[baseA + 4 * k] = o;
    }
    if (okB) {
      const float t = ltv[(eL + 64) * 16 + sw];
      float4 o;
      o.x = ubl(sB0[k]) + t; o.y = ubh(sB0[k]) + t;
      o.z = ubl(sB1[k]) + t; o.w = ubh(sB1[k]) + t;
      o4[baseB + 4 * k] = o;
    }
  }
}

extern "C" void kernel_launch(void* const* d_in, const int* in_sizes, int n_in,
                              void* d_out, int out_size, void* d_ws, size_t ws_size,
                              hipStream_t stream) {
  const float4* x4 = (const float4*)d_in[0];
  const float4* y4 = (const float4*)d_in[1];
  const float* w1p = (const float*)d_in[2];
  const float* w21p = (const float*)d_in[3];
  const float* w22p = (const float*)d_in[4];
  float4* o4 = (float4*)d_out;

  const int E = in_sizes[0] / 256;          // (E, 16, 16) fp32
  const int block = 256;                    // 128 edges per block, 2/thread
  const int grid = (E + 127) / 128;         // 1563 blocks = 6252 waves

  cg2_v18<<<grid, block, 0, stream>>>(x4, y4, w1p, w21p, w22p, o4, E);
}

// Round 14
// 127.314 us; speedup vs baseline: 1.6018x; 1.6018x over previous
//
#include <hip/hip_runtime.h>

// ---------------------------------------------------------------------------
// Compile-time Clebsch-Gordan / real-basis Wigner-3j generation (exact port of
// the Python reference: _cg_coef, _su2_cg, _q, _w3j, normalization, pw).
// ---------------------------------------------------------------------------

struct W3JT { double v[9][9][9]; };

constexpr double dfact(int n) { double r = 1.0; for (int i = 2; i <= n; ++i) r *= (double)i; return r; }

constexpr double csqrt(double x) {
  if (x <= 0.0) return 0.0;
  double g = x > 1.0 ? x : 1.0;
  for (int i = 0; i < 80; ++i) g = 0.5 * (g + x / g);
  return g;
}

constexpr double cg_coef(int j1, int m1, int j2, int m2, int j3, int m3) {
  if (m1 + m2 != m3) return 0.0;
  int vmin = 0;
  if (j2 - j3 - m1 > vmin) vmin = j2 - j3 - m1;
  if (j1 - j3 + m2 > vmin) vmin = j1 - j3 + m2;
  int vmax = j1 + j2 - j3;
  if (j1 - m1 < vmax) vmax = j1 - m1;
  if (j2 + m2 < vmax) vmax = j2 + m2;
  double pref = csqrt((2.0 * j3 + 1.0) * dfact(j3 + j1 - j2) * dfact(j3 - j1 + j2) * dfact(j1 + j2 - j3) / dfact(j1 + j2 + j3 + 1));
  pref *= csqrt(dfact(j3 + m3) * dfact(j3 - m3) * dfact(j1 + m1) * dfact(j1 - m1) * dfact(j2 + m2) * dfact(j2 - m2));
  double s = 0.0;
  for (int v = vmin; v <= vmax; ++v) {
    double t = 1.0 / (dfact(v) * dfact(j1 + j2 - j3 - v) * dfact(j1 - m1 - v) * dfact(j2 + m2 - v) * dfact(j3 - j2 + m1 + v) * dfact(j3 - j1 - m2 + v));
    s += (v & 1) ? -t : t;
  }
  return pref * s;
}

// Nonzero rows of column `col` of the complex->real change-of-basis matrix
// q(l) (each column has <=2 nonzeros), with the (-i)^l phase applied.
struct QCol { int n; int row[2]; double re[2]; double im[2]; };

constexpr QCol qcol(int l, int col) {
  QCol q{};
  const int lm = l & 3;
  const double pr = (lm == 0) ? 1.0 : (lm == 2) ? -1.0 : 0.0;   // Re((-i)^l)
  const double pi = (lm == 1) ? -1.0 : (lm == 3) ? 1.0 : 0.0;   // Im((-i)^l)
  const int mu = col - l;
  const int am = mu < 0 ? -mu : mu;
  const double is2 = 0.70710678118654752440;
  if (mu == 0) {
    q.n = 1; q.row[0] = l;
    q.re[0] = pr; q.im[0] = pi;
  } else {
    const double s = (am & 1) ? -1.0 : 1.0;   // (-1)^|m|
    double a0 = 0.0, b0 = 0.0, a1 = 0.0, b1 = 0.0;
    if (mu > 0) { a0 = is2; b0 = 0.0;  a1 = s * is2; b1 = 0.0; }      // col l+|m|
    else        { a0 = 0.0; b0 = -is2; a1 = 0.0;     b1 = s * is2; }  // col l-|m|
    q.n = 2;
    q.row[0] = l - am; q.row[1] = l + am;
    q.re[0] = a0 * pr - b0 * pi; q.im[0] = a0 * pi + b0 * pr;
    q.re[1] = a1 * pr - b1 * pi; q.im[1] = a1 * pi + b1 * pr;
  }
  return q;
}

constexpr W3JT make_w3j(int l1, int l2, int l3) {
  W3JT R{};
  double C[9][9][9]{};
  for (int m1 = -l1; m1 <= l1; ++m1)
    for (int m2 = -l2; m2 <= l2; ++m2) {
      int m3 = m1 + m2;
      if (m3 >= -l3 && m3 <= l3)
        C[l1 + m1][l2 + m2][l3 + m3] = cg_coef(l1, m1, l2, m2, l3, m3);
    }
  // C_real[j][l][m] = Re( sum q1[i][j] q2[k][l] conj(q3[n][m]) C[i][k][n] )
  double nrm = 0.0;
  for (int j = 0; j < 2 * l1 + 1; ++j) {
    QCol q1 = qcol(l1, j);
    for (int l = 0; l < 2 * l2 + 1; ++l) {
      QCol q2 = qcol(l2, l);
      for (int m = 0; m < 2 * l3 + 1; ++m) {
        QCol q3 = qcol(l3, m);
        double re = 0.0;
        for (int a = 0; a < q1.n; ++a)
          for (int b = 0; b < q2.n; ++b)
            for (int c = 0; c < q3.n; ++c) {
              double cv = C[q1.row[a]][q2.row[b]][q3.row[c]];
              if (cv == 0.0) continue;
              double ar = q1.re[a], ai = q1.im[a];
              double br = q2.re[b], bi = q2.im[b];
              double cr = q3.re[c], ci = -q3.im[c];   // conj
              double abr = ar * br - ai * bi;
              double abi = ar * bi + ai * br;
              double prr = abr * cr - abi * ci;       // Re(triple product)
              re += prr * cv;
            }
        R.v[j][l][m] = re;
        nrm += re * re;
      }
    }
  }
  double n = csqrt(nrm);
  if (n > 0.0)
    for (int j = 0; j < 2 * l1 + 1; ++j)
      for (int l = 0; l < 2 * l2 + 1; ++l)
        for (int m = 0; m < 2 * l3 + 1; ++m)
          R.v[j][l][m] /= n;
  return R;
}

// instruction counts per output-l (verified against the reference enumeration)
// INS1  = instructions(3,3,4): c-counts {4,6,7,6,4}
// INS21 = instructions(3,4,3): c-counts {4,7,8,8}   (INS22 identical)
constexpr int CNT1[5] = {4, 6, 7, 6, 4};
constexpr int CNT2[4] = {4, 7, 8, 8};

#define NZCHK(V) ((V) > 1e-12 || (V) < -1e-12)

// mid[c*c+k] += w1[IDX] * pw * sum_ij W3J[i][j][k] * xm[a*a+i] * ym[b*b+j]
#define TP_MID(IDX, A, B, C) do { \
  constexpr W3JT T = make_w3j(A, B, C); \
  constexpr double PW = csqrt((2.0 * (C) + 1.0) / (double)CNT1[(C)]); \
  const float wi = w1p[IDX]; \
  float u[2 * (A) + 1]; \
  _Pragma("unroll") for (int i = 0; i < 2 * (A) + 1; ++i) u[i] = wi * xm[(A) * (A) + i]; \
  _Pragma("unroll") for (int i = 0; i < 2 * (A) + 1; ++i) { \
    _Pragma("unroll") for (int j = 0; j < 2 * (B) + 1; ++j) { \
      const float p_ = u[i] * ym[(B) * (B) + j]; \
      _Pragma("unroll") for (int k = 0; k < 2 * (C) + 1; ++k) { \
        if (NZCHK(T.v[i][j][k])) \
          mid[(C) * (C) + k] = __builtin_fmaf((float)(T.v[i][j][k] * PW), p_, mid[(C) * (C) + k]); \
      } \
    } \
  } \
} while (0)

// tv[c*c+k] += pw * sum_ij W3J[i][j][k] * (w21[IDX]*xm_i + w22[IDX]*ym_i) * mid_j
#define TP_OUT(IDX, A, B, C) do { \
  constexpr W3JT T = make_w3j(A, B, C); \
  constexpr double PW = csqrt((2.0 * (C) + 1.0) / (double)CNT2[(C)]); \
  const float wa = w21p[IDX]; \
  const float wb = w22p[IDX]; \
  float u[2 * (A) + 1]; \
  _Pragma("unroll") for (int i = 0; i < 2 * (A) + 1; ++i) \
    u[i] = wa * xm[(A) * (A) + i] + wb * ym[(A) * (A) + i]; \
  _Pragma("unroll") for (int i = 0; i < 2 * (A) + 1; ++i) { \
    _Pragma("unroll") for (int j = 0; j < 2 * (B) + 1; ++j) { \
      const float p_ = u[i] * mid[(B) * (B) + j]; \
      _Pragma("unroll") for (int k = 0; k < 2 * (C) + 1; ++k) { \
        if (NZCHK(T.v[i][j][k])) \
          tv[(C) * (C) + k] = __builtin_fmaf((float)(T.v[i][j][k] * PW), p_, tv[(C) * (C) + k]); \
      } \
    } \
  } \
} while (0)

// ---------------------------------------------------------------------------
// v6 (FINAL): block = 256 threads = 64 edges. Best measured: 127.0 us.
//   - s = x+y kept in registers, ONE store at the end (traffic-minimal:
//     FETCH 205 MB + WRITE 205 MB, read-once/write-once via LLC)
//   - chain runs in wave 0 only, one edge per lane (VALU 29% -> 15%)
//  phase 1: coalesced loads (4 lanes/edge, 16B/lane), s in regs,
//           quad-butterfly row means -> LDS (rotate swizzle).
//  phase 2: wave 0: lane q runs the constant-folded chain for edge q, tv->LDS.
//  phase 3: out = s + tv[row], single plain store.
// Structural ceiling: 615 MB mandatory LLC traffic at the ~4.8-5 TB/s this
// 2R:1W mixed stream sustains = 123-128 us. All alternatives (re-read,
// LDS-staged, grid-stride, occupancy-first, multi-edge/thread) measured worse.
// ---------------------------------------------------------------------------
__global__ __launch_bounds__(256) void cg2_v6(
    const float4* __restrict__ x4, const float4* __restrict__ y4,
    const float* __restrict__ w1p, const float* __restrict__ w21p,
    const float* __restrict__ w22p, float4* __restrict__ o4, int E)
{
  __shared__ float lmx[64 * 32];   // xm/ym per edge-in-block, rotate-swizzled
  __shared__ float ltv[64 * 16];   // tv per edge-in-block, rotate-swizzled

  const int eL = threadIdx.x >> 2;        // edge-in-block 0..63
  const int g  = threadIdx.x & 3;         // quad lane
  const int e  = blockIdx.x * 64 + eL;
  const bool ok = (e < E);
  const int base = e * 64 + g;            // float4 index

  // ---- phase 1: loads, s=x+y in regs, row partials ----
  float4 s[16];
  float px[16], py[16];
  if (ok) {
#pragma unroll
    for (int k = 0; k < 16; ++k) {
      const float4 xv = x4[base + 4 * k];
      const float4 yv = y4[base + 4 * k];
      s[k].x = xv.x + yv.x; s[k].y = xv.y + yv.y;
      s[k].z = xv.z + yv.z; s[k].w = xv.w + yv.w;
      px[k] = (xv.x + xv.y) + (xv.z + xv.w);
      py[k] = (yv.x + yv.y) + (yv.z + yv.w);
    }
  } else {
#pragma unroll
    for (int k = 0; k < 16; ++k) { px[k] = 0.f; py[k] = 0.f; }
  }

  // quad butterflies -> full row means (replicated in all 4 lanes)
#pragma unroll
  for (int k = 0; k < 16; ++k) {
    float rx = px[k] + __shfl_xor(px[k], 1);
    rx += __shfl_xor(rx, 2);
    float ry = py[k] + __shfl_xor(py[k], 1);
    ry += __shfl_xor(ry, 2);
    px[k] = rx * (1.0f / 16.0f);
    py[k] = ry * (1.0f / 16.0f);
  }

  // write xm (slots 0..15) and ym (slots 16..31): thread g covers j=4g..4g+3
  if (ok) {
#pragma unroll
    for (int u = 0; u < 4; ++u) {
      const int j = 4 * g + u;
      lmx[eL * 32 + ((j + eL) & 31)]      = px[j];
      lmx[eL * 32 + ((16 + j + eL) & 31)] = py[j];
    }
  }
  __syncthreads();

  // ---- phase 2: wave 0 runs the chain, one edge per lane ----
  if (threadIdx.x < 64) {
    const int q = threadIdx.x;
    const bool ok2 = (blockIdx.x * 64 + q < E);
    float xm[16], ym[16];
#pragma unroll
    for (int j = 0; j < 16; ++j) xm[j] = lmx[q * 32 + ((j + q) & 31)];
#pragma unroll
    for (int j = 0; j < 16; ++j) ym[j] = lmx[q * 32 + ((16 + j + q) & 31)];

    float mid[25];
#pragma unroll
    for (int k = 0; k < 25; ++k) mid[k] = 0.f;

    // INS1 = instructions(3,3,4), reference order
    TP_MID( 0, 0, 0, 0);
    TP_MID( 1, 0, 1, 1);
    TP_MID( 2, 0, 2, 2);
    TP_MID( 3, 0, 3, 3);
    TP_MID( 4, 1, 0, 1);
    TP_MID( 5, 1, 1, 0);
    TP_MID( 6, 1, 1, 2);
    TP_MID( 7, 1, 2, 1);
    TP_MID( 8, 1, 2, 3);
    TP_MID( 9, 1, 3, 2);
    TP_MID(10, 1, 3, 4);
    TP_MID(11, 2, 0, 2);
    TP_MID(12, 2, 1, 1);
    TP_MID(13, 2, 1, 3);
    TP_MID(14, 2, 2, 0);
    TP_MID(15, 2, 2, 2);
    TP_MID(16, 2, 2, 4);
    TP_MID(17, 2, 3, 1);
    TP_MID(18, 2, 3, 3);
    TP_MID(19, 3, 0, 3);
    TP_MID(20, 3, 1, 2);
    TP_MID(21, 3, 1, 4);
    TP_MID(22, 3, 2, 1);
    TP_MID(23, 3, 2, 3);
    TP_MID(24, 3, 3, 0);
    TP_MID(25, 3, 3, 2);
    TP_MID(26, 3, 3, 4);

    float tv[16];
#pragma unroll
    for (int k = 0; k < 16; ++k) tv[k] = 0.f;

    // INS21 == INS22 = instructions(3,4,3); fused via u = w21*xm + w22*ym
    TP_OUT( 0, 0, 0, 0);
    TP_OUT( 1, 0, 1, 1);
    TP_OUT( 2, 0, 2, 2);
    TP_OUT( 3, 0, 3, 3);
    TP_OUT( 4, 1, 0, 1);
    TP_OUT( 5, 1, 1, 0);
    TP_OUT( 6, 1, 1, 2);
    TP_OUT( 7, 1, 2, 1);
    TP_OUT( 8, 1, 2, 3);
    TP_OUT( 9, 1, 3, 2);
    TP_OUT(10, 1, 4, 3);
    TP_OUT(11, 2, 0, 2);
    TP_OUT(12, 2, 1, 1);
    TP_OUT(13, 2, 1, 3);
    TP_OUT(14, 2, 2, 0);
    TP_OUT(15, 2, 2, 2);
    TP_OUT(16, 2, 3, 1);
    TP_OUT(17, 2, 3, 3);
    TP_OUT(18, 2, 4, 2);
    TP_OUT(19, 3, 0, 3);
    TP_OUT(20, 3, 1, 2);
    TP_OUT(21, 3, 2, 1);
    TP_OUT(22, 3, 2, 3);
    TP_OUT(23, 3, 3, 0);
    TP_OUT(24, 3, 3, 2);
    TP_OUT(25, 3, 4, 1);
    TP_OUT(26, 3, 4, 3);

    if (ok2) {
#pragma unroll
      for (int k = 0; k < 16; ++k) ltv[q * 16 + ((k + q) & 15)] = tv[k];
    }
  }
  __syncthreads();

  // ---- phase 3: out = s + tv[row], single store ----
  if (ok) {
#pragma unroll
    for (int k = 0; k < 16; ++k) {
      const float t = ltv[eL * 16 + ((k + eL) & 15)];
      float4 o;
      o.x = s[k].x + t;
      o.y = s[k].y + t;
      o.z = s[k].z + t;
      o.w = s[k].w + t;
      o4[base + 4 * k] = o;
    }
  }
}

extern "C" void kernel_launch(void* const* d_in, const int* in_sizes, int n_in,
                              void* d_out, int out_size, void* d_ws, size_t ws_size,
                              hipStream_t stream) {
  const float4* x4 = (const float4*)d_in[0];
  const float4* y4 = (const float4*)d_in[1];
  const float* w1p = (const float*)d_in[2];
  const float* w21p = (const float*)d_in[3];
  const float* w22p = (const float*)d_in[4];
  float4* o4 = (float4*)d_out;

  const int E = in_sizes[0] / 256;          // (E, 16, 16) fp32
  const int block = 256;                    // 64 edges per block
  const int grid = (E + 63) / 64;

  cg2_v6<<<grid, block, 0, stream>>>(x4, y4, w1p, w21p, w22p, o4, E);
}